// Round 3
// baseline (541.358 us; speedup 1.0000x reference)
//
#include <hip/hip_runtime.h>

// out[b,k,n,m] = exp(-0.1*sqrt(max(|An|^2 - 2 An.Am + |Am|^2, 1e-6))), clipped to [0,1]
// A = x*msk, x:(8,64,512,16) fp32. Output (8,64,512,512,1) fp32 = 512 MiB -> write-bound (~85us).
//
// MFMA design: K=16 == one v_mfma_f32_32x32x16_f16 per 32x32 output subtile (no K loop).
// One block per half-slice (256 rows x 512 cols): stage all 512 nodes once (f32->f16 + mask,
// norms from the CAST values so the diagonal cancels), single barrier, then each of 4 waves
// computes 2 row-bands x 16 col-subtiles. Epilogue fused per-lane on the 16 D regs;
// nontemporal dword stores (32-lane-contiguous 128B segments).
// f16 error bound: |d_err| <= 2^-11*(|a|+|b|) ~ 4e-3 -> |out_err| <= 4e-4 << 2e-2 threshold.

typedef float    f32x4  __attribute__((ext_vector_type(4)));
typedef float    f32x16 __attribute__((ext_vector_type(16)));
typedef _Float16 f16x8  __attribute__((ext_vector_type(8)));

#define NEG_DIST_LOG2E (-0.14426950408889634f)  // -0.1 * log2(e)
#define EPS_F 1e-6f
#define NSTRIDE 24   // f16 elems per node in LDS: 16 data + 8 pad = 48 B (16B-aligned, conflict-benign)

__global__ __launch_bounds__(256, 4) void node_pair_gaussian_mfma(
    const float* __restrict__ x,    // (512 slices, 512 nodes, 16 f)
    const float* __restrict__ msk,  // (512 slices, 512 nodes)
    float* __restrict__ out)        // (512 slices, 512, 512)
{
    __shared__ _Float16 af[512 * NSTRIDE];  // 24 KiB
    __shared__ float    na[512];            // 2 KiB

    const int tid   = threadIdx.x;          // 0..255
    const int slice = blockIdx.x >> 1;      // 0..511
    const int half  = blockIdx.x & 1;       // row half of the slice

    const float* xs = x   + (size_t)slice * (512 * 16);
    const float* ms = msk + (size_t)slice * 512;

    // ---- Stage all 512 nodes: mask, cast f32->f16, per-node |a|^2 from cast values ----
    #pragma unroll
    for (int it = 0; it < 2; ++it) {
        const int node = it * 256 + tid;
        const float mm = ms[node];
        const f32x4 v0 = *(const f32x4*)(xs + node * 16 +  0) * mm;
        const f32x4 v1 = *(const f32x4*)(xs + node * 16 +  4) * mm;
        const f32x4 v2 = *(const f32x4*)(xs + node * 16 +  8) * mm;
        const f32x4 v3 = *(const f32x4*)(xs + node * 16 + 12) * mm;
        const float vv[16] = {v0.x, v0.y, v0.z, v0.w, v1.x, v1.y, v1.z, v1.w,
                              v2.x, v2.y, v2.z, v2.w, v3.x, v3.y, v3.z, v3.w};
        f16x8 h0, h1;
        float s = 0.0f;
        #pragma unroll
        for (int f = 0; f < 8; ++f) {
            const _Float16 h = (_Float16)vv[f];
            h0[f] = h;
            const float hf = (float)h;
            s = fmaf(hf, hf, s);
        }
        #pragma unroll
        for (int f = 0; f < 8; ++f) {
            const _Float16 h = (_Float16)vv[8 + f];
            h1[f] = h;
            const float hf = (float)h;
            s = fmaf(hf, hf, s);
        }
        *(f16x8*)&af[node * NSTRIDE + 0] = h0;
        *(f16x8*)&af[node * NSTRIDE + 8] = h1;
        na[node] = s;
    }
    __syncthreads();

    // ---- MFMA main: wave computes 2 row-bands (32 rows) x 16 col-subtiles (32 cols) ----
    const int wave  = tid >> 6;   // 0..3
    const int lane  = tid & 63;
    const int ln31  = lane & 31;
    const int khalf = lane >> 5;  // k-block: lanes 0-31 -> k 0..7, lanes 32-63 -> k 8..15

    float* outs = out + (size_t)slice * (512 * 512);

    #pragma unroll
    for (int band = 0; band < 2; ++band) {
        const int row0 = half * 256 + (wave * 2 + band) * 32;
        // A-frag: A[m = ln31][k = khalf*8 + j]
        const f16x8 afrag = *(const f16x8*)&af[(row0 + ln31) * NSTRIDE + khalf * 8];
        // Row-norms for this lane's 16 output rows: row = g*8 + khalf*4 + q
        f32x4 nn[4];
        #pragma unroll
        for (int g = 0; g < 4; ++g)
            nn[g] = *(const f32x4*)&na[row0 + g * 8 + khalf * 4];

        for (int c = 0; c < 16; ++c) {
            // B-frag: B[k = khalf*8 + j][n = ln31]  (B = A^T -> same gather as A)
            const f16x8 bfrag = *(const f16x8*)&af[(c * 32 + ln31) * NSTRIDE + khalf * 8];
            const float tm = na[c * 32 + ln31];   // col-norm for this lane's column

            f32x16 acc;
            #pragma unroll
            for (int i = 0; i < 16; ++i) acc[i] = 0.0f;
            acc = __builtin_amdgcn_mfma_f32_32x32x16_f16(afrag, bfrag, acc, 0, 0, 0);

            // D layout: col = ln31, row = (r&3) + 8*(r>>2) + 4*khalf  [m74/m101 verified]
            float* colp = outs + (size_t)(row0 + khalf * 4) * 512 + c * 32 + ln31;
            #pragma unroll
            for (int r = 0; r < 16; ++r) {
                const int g = r >> 2, q = r & 3;
                const float pre = nn[g][q] + tm;
                float s = fmaf(-2.0f, acc[r], pre);
                s = fmaxf(s, EPS_F);
                const float d = __builtin_amdgcn_sqrtf(s);
                const float e = __builtin_amdgcn_exp2f(d * NEG_DIST_LOG2E);
                // e = exp2(negative) < 1 and > 0 always -> clip is a no-op
                __builtin_nontemporal_store(e, colp + (size_t)(g * 8 + q) * 512);
            }
        }
    }
}

extern "C" void kernel_launch(void* const* d_in, const int* in_sizes, int n_in,
                              void* d_out, int out_size, void* d_ws, size_t ws_size,
                              hipStream_t stream) {
    const float* x   = (const float*)d_in[0];   // (8,64,512,16) fp32
    const float* msk = (const float*)d_in[1];   // (8,64,512,1)  fp32
    float* out = (float*)d_out;                 // (8,64,512,512,1) fp32

    // 2 blocks per slice (256-row halves), 512 slices
    node_pair_gaussian_mfma<<<1024, 256, 0, stream>>>(x, msk, out);
}